// Round 9
// baseline (175.136 us; speedup 1.0000x reference)
//
#include <hip/hip_runtime.h>

#define FDIM 16
#define RPB  64     // rows per block
#define NT   512    // threads per block = 64 groups x 8 lanes
#define CAP  2048   // LDS edge-tile capacity (block span ~1024 expected)

// ---------------------------------------------------------------------------
// Kernel A: build CSR row_ptr from the SORTED COO row array.
// ---------------------------------------------------------------------------
__global__ __launch_bounds__(256) void rowptr_kernel(const int* __restrict__ rows,
                                                     int* __restrict__ row_ptr,
                                                     long long nedge, int n) {
  long long e = (long long)blockIdx.x * blockDim.x + threadIdx.x;
  if (e >= nedge) return;
  int b = rows[e];
  if (e == 0) {
    for (int r = 0; r <= b; ++r) row_ptr[r] = 0;
  } else {
    int a = rows[e - 1];
    for (int r = a + 1; r <= b; ++r) row_ptr[r] = (int)e;
  }
  if (e == nedge - 1) {
    for (int r = b + 1; r <= n; ++r) row_ptr[r] = (int)nedge;
  }
}

// ---------------------------------------------------------------------------
// Kernel B: fused CSR SpMM + GCNII epilogue.
// Block = 512 threads = 64 groups x 8 lanes; lane = feature pair {2l,2l+1}.
// The `rows` array is never read here: row boundaries come from the block's
// row_ptr window staged in LDS (binary search for slice start, threshold
// compare per chunk). Edge tile (cols+vals) staged coalesced in LDS; tile
// edges split EVENLY across 64 groups; register run-accumulate, LDS-atomic
// flush into lhi[64][16]; in-register epilogue per group.
// ---------------------------------------------------------------------------
__global__ __launch_bounds__(NT) void spmm_fuse_kernel(
    const int* __restrict__ row_ptr,
    const int* __restrict__ cols,
    const float* __restrict__ vals,
    const float* __restrict__ x,
    const float* __restrict__ h0,
    const float* __restrict__ weight,
    const float* __restrict__ fc_w,
    const float* __restrict__ fc_b,
    const float* __restrict__ lamda,
    const int* __restrict__ lpar,
    float* __restrict__ out,
    int n) {
  __shared__ float wsh[2 * FDIM * FDIM];   // 2 KB weight
  __shared__ int   lrp[RPB + 1];           // 260 B row_ptr window
  __shared__ int   lc[CAP];                // 8 KB cols
  __shared__ float lv[CAP];                // 8 KB vals
  __shared__ float lhi[RPB][FDIM];         // 4 KB accumulators

  int tid = (int)threadIdx.x;
  int R0 = blockIdx.x * RPB;
  for (int i = tid; i < 2 * FDIM * FDIM; i += NT) wsh[i] = weight[i];
  for (int i = tid; i < RPB * FDIM; i += NT) ((float*)lhi)[i] = 0.f;
  for (int i = tid; i <= RPB; i += NT) lrp[i] = row_ptr[min(R0 + i, n)];
  __syncthreads();

  int g = tid >> 3;    // group 0..63
  int l = tid & 7;     // lane 0..7
  int s_blk = lrp[0];
  int t_blk = lrp[RPB];

  const float2* __restrict__ x2 = reinterpret_cast<const float2*>(x);

  for (int t0 = s_blk; t0 < t_blk; t0 += CAP) {
    int t1 = min(t0 + CAP, t_blk);
    int len = t1 - t0;
    for (int i = tid; i < len; i += NT) {
      lc[i] = cols[t0 + i];
      lv[i] = vals[t0 + i];
    }
    __syncthreads();

    int a = (len * g) >> 6;        // even split among 64 groups
    int b = (len * (g + 1)) >> 6;
    if (a < b) {
      // binary search in lrp: cur with lrp[cur] <= t0+a < lrp[cur+1]
      int ge0 = t0 + a;
      int lo = 0, hi = RPB;
      while (hi - lo > 1) {
        int mid = (lo + hi) >> 1;
        if (lrp[mid] <= ge0) lo = mid; else hi = mid;
      }
      int cur = lo;
      int nxt = lrp[cur + 1];
      float ax = 0.f, ay = 0.f;

#define FLUSH()                                   \
      { atomicAdd(&lhi[cur][2 * l],     ax);      \
        atomicAdd(&lhi[cur][2 * l + 1], ay);      \
        ax = 0.f; ay = 0.f; }
#define ADV(gl_)                                  \
      if (gl_ >= nxt) {                           \
        FLUSH();                                  \
        do { ++cur; nxt = lrp[cur + 1]; } while (gl_ >= nxt); \
      }

      int e = a;
      for (; e + 8 <= b; e += 8) {
        int   c0 = lc[e+0], c1 = lc[e+1], c2 = lc[e+2], c3 = lc[e+3];
        int   c4 = lc[e+4], c5 = lc[e+5], c6 = lc[e+6], c7 = lc[e+7];
        float v0 = lv[e+0], v1 = lv[e+1], v2 = lv[e+2], v3 = lv[e+3];
        float v4 = lv[e+4], v5 = lv[e+5], v6 = lv[e+6], v7 = lv[e+7];
        float2 g0 = x2[c0 * 8 + l], g1 = x2[c1 * 8 + l];
        float2 g2 = x2[c2 * 8 + l], g3 = x2[c3 * 8 + l];
        float2 g4 = x2[c4 * 8 + l], g5 = x2[c5 * 8 + l];
        float2 g6 = x2[c6 * 8 + l], g7 = x2[c7 * 8 + l];
        if (t0 + e + 7 < nxt) {     // whole chunk inside current row
          ax = fmaf(v0, g0.x, ax); ay = fmaf(v0, g0.y, ay);
          ax = fmaf(v1, g1.x, ax); ay = fmaf(v1, g1.y, ay);
          ax = fmaf(v2, g2.x, ax); ay = fmaf(v2, g2.y, ay);
          ax = fmaf(v3, g3.x, ax); ay = fmaf(v3, g3.y, ay);
          ax = fmaf(v4, g4.x, ax); ay = fmaf(v4, g4.y, ay);
          ax = fmaf(v5, g5.x, ax); ay = fmaf(v5, g5.y, ay);
          ax = fmaf(v6, g6.x, ax); ay = fmaf(v6, g6.y, ay);
          ax = fmaf(v7, g7.x, ax); ay = fmaf(v7, g7.y, ay);
        } else {
          ADV(t0 + e + 0) ax = fmaf(v0, g0.x, ax); ay = fmaf(v0, g0.y, ay);
          ADV(t0 + e + 1) ax = fmaf(v1, g1.x, ax); ay = fmaf(v1, g1.y, ay);
          ADV(t0 + e + 2) ax = fmaf(v2, g2.x, ax); ay = fmaf(v2, g2.y, ay);
          ADV(t0 + e + 3) ax = fmaf(v3, g3.x, ax); ay = fmaf(v3, g3.y, ay);
          ADV(t0 + e + 4) ax = fmaf(v4, g4.x, ax); ay = fmaf(v4, g4.y, ay);
          ADV(t0 + e + 5) ax = fmaf(v5, g5.x, ax); ay = fmaf(v5, g5.y, ay);
          ADV(t0 + e + 6) ax = fmaf(v6, g6.x, ax); ay = fmaf(v6, g6.y, ay);
          ADV(t0 + e + 7) ax = fmaf(v7, g7.x, ax); ay = fmaf(v7, g7.y, ay);
        }
      }
      for (; e < b; ++e) {
        float2 gg = x2[lc[e] * 8 + l];
        float  vv = lv[e];
        ADV(t0 + e)
        ax = fmaf(vv, gg.x, ax); ay = fmaf(vv, gg.y, ay);
      }
      FLUSH();
#undef ADV
#undef FLUSH
    }
    __syncthreads();   // slice consumption done before next tile overwrite
  }

  __syncthreads();     // lhi final before epilogue reads

  int r = R0 + g;
  if (r >= n) return;

  float2 hi2 = make_float2(lhi[g][2 * l], lhi[g][2 * l + 1]);
  float2 h02 = reinterpret_cast<const float2*>(h0)[(size_t)r * 8 + l];
  float2 xf2 = reinterpret_cast<const float2*>(x)[(size_t)r * 8 + l];
  float theta = logf(lamda[0] / (float)lpar[0] + 1.0f);

  // alpha = hi . fc_w + fc_b  (8-lane reduce over feature pairs)
  float av = hi2.x * fc_w[2 * l] + hi2.y * fc_w[2 * l + 1];
  av += __shfl_xor(av, 1, 8);
  av += __shfl_xor(av, 2, 8);
  av += __shfl_xor(av, 4, 8);
  float alpha = av + fc_b[0];

  // s[f] = sum_k hi[k]*W[k,f] + h0[k]*W[16+k,f]   (f = 2l, 2l+1)
  const float2* wsh2 = reinterpret_cast<const float2*>(wsh);
  float sx = 0.f, sy = 0.f;
#pragma unroll
  for (int k = 0; k < FDIM; ++k) {
    float hk  = lhi[g][k];                                   // LDS broadcast
    float h0k = (k & 1) ? __shfl(h02.y, k >> 1, 8)
                        : __shfl(h02.x, k >> 1, 8);
    float2 w1 = wsh2[k * 8 + l];
    float2 w2 = wsh2[(FDIM + k) * 8 + l];
    sx = fmaf(hk, w1.x, sx);  sy = fmaf(hk, w1.y, sy);
    sx = fmaf(h0k, w2.x, sx); sy = fmaf(h0k, w2.y, sy);
  }

  float rx = (1.f - alpha) * hi2.x + alpha * h02.x;
  float ry = (1.f - alpha) * hi2.y + alpha * h02.y;
  float2 o;
  o.x = fmaf(theta, sx, (1.f - theta) * rx) + xf2.x;
  o.y = fmaf(theta, sy, (1.f - theta) * ry) + xf2.y;
  reinterpret_cast<float2*>(out)[(size_t)r * 8 + l] = o;
}

extern "C" void kernel_launch(void* const* d_in, const int* in_sizes, int n_in,
                              void* d_out, int out_size, void* d_ws, size_t ws_size,
                              hipStream_t stream) {
  const float* x        = (const float*)d_in[0];
  const float* h0       = (const float*)d_in[1];
  const int* adj_row    = (const int*)d_in[2];   // int32 (JAX x64 disabled)
  const int* adj_col    = (const int*)d_in[3];   // int32
  const float* adj_val  = (const float*)d_in[4];
  const float* weight   = (const float*)d_in[5];
  const float* fc_w     = (const float*)d_in[6];
  const float* fc_b     = (const float*)d_in[7];
  const float* lamda    = (const float*)d_in[8];
  const int* lpar       = (const int*)d_in[9];

  int n = in_sizes[0] / FDIM;
  long long nedge = in_sizes[2];
  float* out = (float*)d_out;
  int* row_ptr = (int*)d_ws;   // (n+1) ints = 2 MB, rebuilt every call

  long long rb = (nedge + 255) / 256;
  rowptr_kernel<<<(int)rb, 256, 0, stream>>>(adj_row, row_ptr, nedge, n);

  int sb = (n + RPB - 1) / RPB;
  spmm_fuse_kernel<<<sb, NT, 0, stream>>>(row_ptr, adj_col, adj_val,
                                          x, h0, weight, fc_w, fc_b, lamda,
                                          lpar, out, n);
}

// Round 10
// 174.493 us; speedup vs baseline: 1.0037x; 1.0037x over previous
//
#include <hip/hip_runtime.h>
#include <hip/hip_fp16.h>

#define FDIM 16
#define RPB  64     // rows per block
#define NT   512    // threads per block = 64 groups x 8 lanes
#define CAP  2048   // LDS edge-tile capacity (block span ~1024 expected)

// ---------------------------------------------------------------------------
// Kernel A: build CSR row_ptr from the SORTED COO row array.
// ---------------------------------------------------------------------------
__global__ __launch_bounds__(256) void rowptr_kernel(const int* __restrict__ rows,
                                                     int* __restrict__ row_ptr,
                                                     long long nedge, int n) {
  long long e = (long long)blockIdx.x * blockDim.x + threadIdx.x;
  if (e >= nedge) return;
  int b = rows[e];
  if (e == 0) {
    for (int r = 0; r <= b; ++r) row_ptr[r] = 0;
  } else {
    int a = rows[e - 1];
    for (int r = a + 1; r <= b; ++r) row_ptr[r] = (int)e;
  }
  if (e == nedge - 1) {
    for (int r = b + 1; r <= n; ++r) row_ptr[r] = (int)nedge;
  }
}

// ---------------------------------------------------------------------------
// Kernel C: convert x (f32) -> xh (fp16), 8 elements/thread, 16B stores.
// ---------------------------------------------------------------------------
__global__ __launch_bounds__(256) void cvt_kernel(const float* __restrict__ xin,
                                                  __half* __restrict__ xout,
                                                  long long nelem) {
  long long i = ((long long)blockIdx.x * 256 + threadIdx.x) * 8;
  if (i + 8 > nelem) return;
  float4 a = *reinterpret_cast<const float4*>(xin + i);
  float4 b = *reinterpret_cast<const float4*>(xin + i + 4);
  __half2 h0 = __floats2half2_rn(a.x, a.y);
  __half2 h1 = __floats2half2_rn(a.z, a.w);
  __half2 h2 = __floats2half2_rn(b.x, b.y);
  __half2 h3 = __floats2half2_rn(b.z, b.w);
  __half2* o = reinterpret_cast<__half2*>(xout + i);
  o[0] = h0; o[1] = h1; o[2] = h2; o[3] = h3;
}

// ---------------------------------------------------------------------------
// Kernel B: fused CSR SpMM + GCNII epilogue (r9 structure).
// USE_H: gather from fp16 copy of x (32B/edge) instead of f32 (64B/edge) —
// probes whether the ~3.2 TB/s plateau is byte-bound or granule-bound.
// ---------------------------------------------------------------------------
template <bool USE_H>
__global__ __launch_bounds__(NT) void spmm_fuse_kernel(
    const int* __restrict__ row_ptr,
    const int* __restrict__ cols,
    const float* __restrict__ vals,
    const float* __restrict__ x,
    const __half* __restrict__ xh,
    const float* __restrict__ h0,
    const float* __restrict__ weight,
    const float* __restrict__ fc_w,
    const float* __restrict__ fc_b,
    const float* __restrict__ lamda,
    const int* __restrict__ lpar,
    float* __restrict__ out,
    int n) {
  __shared__ float wsh[2 * FDIM * FDIM];   // 2 KB weight
  __shared__ int   lrp[RPB + 1];           // row_ptr window
  __shared__ int   lc[CAP];                // 8 KB cols
  __shared__ float lv[CAP];                // 8 KB vals
  __shared__ float lhi[RPB][FDIM];         // 4 KB accumulators

  int tid = (int)threadIdx.x;
  int R0 = blockIdx.x * RPB;
  for (int i = tid; i < 2 * FDIM * FDIM; i += NT) wsh[i] = weight[i];
  for (int i = tid; i < RPB * FDIM; i += NT) ((float*)lhi)[i] = 0.f;
  for (int i = tid; i <= RPB; i += NT) lrp[i] = row_ptr[min(R0 + i, n)];
  __syncthreads();

  int g = tid >> 3;    // group 0..63
  int l = tid & 7;     // lane 0..7
  int s_blk = lrp[0];
  int t_blk = lrp[RPB];

  const float2*  __restrict__ x2  = reinterpret_cast<const float2*>(x);
  const __half2* __restrict__ xh2 = reinterpret_cast<const __half2*>(xh);

  auto ld = [&](int c) -> float2 {
    if constexpr (USE_H) return __half22float2(xh2[(size_t)c * 8 + l]);
    else                 return x2[(size_t)c * 8 + l];
  };

  for (int t0 = s_blk; t0 < t_blk; t0 += CAP) {
    int t1 = min(t0 + CAP, t_blk);
    int len = t1 - t0;
    for (int i = tid; i < len; i += NT) {
      lc[i] = cols[t0 + i];
      lv[i] = vals[t0 + i];
    }
    __syncthreads();

    int a = (len * g) >> 6;        // even split among 64 groups
    int b = (len * (g + 1)) >> 6;
    if (a < b) {
      int ge0 = t0 + a;
      int lo = 0, hi = RPB;
      while (hi - lo > 1) {
        int mid = (lo + hi) >> 1;
        if (lrp[mid] <= ge0) lo = mid; else hi = mid;
      }
      int cur = lo;
      int nxt = lrp[cur + 1];
      float ax = 0.f, ay = 0.f;

#define FLUSH()                                   \
      { atomicAdd(&lhi[cur][2 * l],     ax);      \
        atomicAdd(&lhi[cur][2 * l + 1], ay);      \
        ax = 0.f; ay = 0.f; }
#define ADV(gl_)                                  \
      if (gl_ >= nxt) {                           \
        FLUSH();                                  \
        do { ++cur; nxt = lrp[cur + 1]; } while (gl_ >= nxt); \
      }

      int e = a;
      for (; e + 8 <= b; e += 8) {
        int   c0 = lc[e+0], c1 = lc[e+1], c2 = lc[e+2], c3 = lc[e+3];
        int   c4 = lc[e+4], c5 = lc[e+5], c6 = lc[e+6], c7 = lc[e+7];
        float v0 = lv[e+0], v1 = lv[e+1], v2 = lv[e+2], v3 = lv[e+3];
        float v4 = lv[e+4], v5 = lv[e+5], v6 = lv[e+6], v7 = lv[e+7];
        float2 g0 = ld(c0), g1 = ld(c1), g2 = ld(c2), g3 = ld(c3);
        float2 g4 = ld(c4), g5 = ld(c5), g6 = ld(c6), g7 = ld(c7);
        if (t0 + e + 7 < nxt) {     // whole chunk inside current row
          ax = fmaf(v0, g0.x, ax); ay = fmaf(v0, g0.y, ay);
          ax = fmaf(v1, g1.x, ax); ay = fmaf(v1, g1.y, ay);
          ax = fmaf(v2, g2.x, ax); ay = fmaf(v2, g2.y, ay);
          ax = fmaf(v3, g3.x, ax); ay = fmaf(v3, g3.y, ay);
          ax = fmaf(v4, g4.x, ax); ay = fmaf(v4, g4.y, ay);
          ax = fmaf(v5, g5.x, ax); ay = fmaf(v5, g5.y, ay);
          ax = fmaf(v6, g6.x, ax); ay = fmaf(v6, g6.y, ay);
          ax = fmaf(v7, g7.x, ax); ay = fmaf(v7, g7.y, ay);
        } else {
          ADV(t0 + e + 0) ax = fmaf(v0, g0.x, ax); ay = fmaf(v0, g0.y, ay);
          ADV(t0 + e + 1) ax = fmaf(v1, g1.x, ax); ay = fmaf(v1, g1.y, ay);
          ADV(t0 + e + 2) ax = fmaf(v2, g2.x, ax); ay = fmaf(v2, g2.y, ay);
          ADV(t0 + e + 3) ax = fmaf(v3, g3.x, ax); ay = fmaf(v3, g3.y, ay);
          ADV(t0 + e + 4) ax = fmaf(v4, g4.x, ax); ay = fmaf(v4, g4.y, ay);
          ADV(t0 + e + 5) ax = fmaf(v5, g5.x, ax); ay = fmaf(v5, g5.y, ay);
          ADV(t0 + e + 6) ax = fmaf(v6, g6.x, ax); ay = fmaf(v6, g6.y, ay);
          ADV(t0 + e + 7) ax = fmaf(v7, g7.x, ax); ay = fmaf(v7, g7.y, ay);
        }
      }
      for (; e < b; ++e) {
        float2 gg = ld(lc[e]);
        float  vv = lv[e];
        ADV(t0 + e)
        ax = fmaf(vv, gg.x, ax); ay = fmaf(vv, gg.y, ay);
      }
      FLUSH();
#undef ADV
#undef FLUSH
    }
    __syncthreads();   // slice consumption done before next tile overwrite
  }

  __syncthreads();     // lhi final before epilogue reads

  int r = R0 + g;
  if (r >= n) return;

  float2 hi2 = make_float2(lhi[g][2 * l], lhi[g][2 * l + 1]);
  float2 h02 = reinterpret_cast<const float2*>(h0)[(size_t)r * 8 + l];
  float2 xf2 = reinterpret_cast<const float2*>(x)[(size_t)r * 8 + l];
  float theta = logf(lamda[0] / (float)lpar[0] + 1.0f);

  float av = hi2.x * fc_w[2 * l] + hi2.y * fc_w[2 * l + 1];
  av += __shfl_xor(av, 1, 8);
  av += __shfl_xor(av, 2, 8);
  av += __shfl_xor(av, 4, 8);
  float alpha = av + fc_b[0];

  const float2* wsh2 = reinterpret_cast<const float2*>(wsh);
  float sx = 0.f, sy = 0.f;
#pragma unroll
  for (int k = 0; k < FDIM; ++k) {
    float hk  = lhi[g][k];
    float h0k = (k & 1) ? __shfl(h02.y, k >> 1, 8)
                        : __shfl(h02.x, k >> 1, 8);
    float2 w1 = wsh2[k * 8 + l];
    float2 w2 = wsh2[(FDIM + k) * 8 + l];
    sx = fmaf(hk, w1.x, sx);  sy = fmaf(hk, w1.y, sy);
    sx = fmaf(h0k, w2.x, sx); sy = fmaf(h0k, w2.y, sy);
  }

  float rx = (1.f - alpha) * hi2.x + alpha * h02.x;
  float ry = (1.f - alpha) * hi2.y + alpha * h02.y;
  float2 o;
  o.x = fmaf(theta, sx, (1.f - theta) * rx) + xf2.x;
  o.y = fmaf(theta, sy, (1.f - theta) * ry) + xf2.y;
  reinterpret_cast<float2*>(out)[(size_t)r * 8 + l] = o;
}

extern "C" void kernel_launch(void* const* d_in, const int* in_sizes, int n_in,
                              void* d_out, int out_size, void* d_ws, size_t ws_size,
                              hipStream_t stream) {
  const float* x        = (const float*)d_in[0];
  const float* h0       = (const float*)d_in[1];
  const int* adj_row    = (const int*)d_in[2];   // int32 (JAX x64 disabled)
  const int* adj_col    = (const int*)d_in[3];   // int32
  const float* adj_val  = (const float*)d_in[4];
  const float* weight   = (const float*)d_in[5];
  const float* fc_w     = (const float*)d_in[6];
  const float* fc_b     = (const float*)d_in[7];
  const float* lamda    = (const float*)d_in[8];
  const int* lpar       = (const int*)d_in[9];

  int n = in_sizes[0] / FDIM;
  long long nedge = in_sizes[2];
  long long nelem = (long long)n * FDIM;
  float* out = (float*)d_out;

  size_t xh_bytes = (size_t)nelem * 2;                  // 16 MB
  size_t need = xh_bytes + (size_t)(n + 1) * 4;         // + row_ptr
  bool useh = ws_size >= need;

  __half* xh   = (__half*)d_ws;
  int* row_ptr = (int*)((char*)d_ws + (useh ? xh_bytes : 0));

  long long rb = (nedge + 255) / 256;
  rowptr_kernel<<<(int)rb, 256, 0, stream>>>(adj_row, row_ptr, nedge, n);

  if (useh) {
    long long cb = (nelem / 8 + 255) / 256;
    cvt_kernel<<<(int)cb, 256, 0, stream>>>(x, xh, nelem);
  }

  int sb = (n + RPB - 1) / RPB;
  if (useh) {
    spmm_fuse_kernel<true><<<sb, NT, 0, stream>>>(row_ptr, adj_col, adj_val,
                                                  x, xh, h0, weight, fc_w,
                                                  fc_b, lamda, lpar, out, n);
  } else {
    spmm_fuse_kernel<false><<<sb, NT, 0, stream>>>(row_ptr, adj_col, adj_val,
                                                   x, xh, h0, weight, fc_w,
                                                   fc_b, lamda, lpar, out, n);
  }
}